// Round 10
// baseline (2341.866 us; speedup 1.0000x reference)
//
#include <hip/hip_runtime.h>

#define N_ 1024
#define D_ 128
#define K_ 256
#define M_ 4
#define H_ 256
#define NB_ 2
#define KT_ 32
#define EPS_ 1.0f
#define CHPAD 136
#define HPAD  264

typedef _Float16 half8 __attribute__((ext_vector_type(8)));
typedef __attribute__((ext_vector_type(8))) short short8;
typedef __attribute__((ext_vector_type(4))) float f32x4;
typedef __attribute__((ext_vector_type(16))) float f32x16;

__device__ inline float s2f(unsigned short s) {
    return (float)__builtin_bit_cast(_Float16, s);
}
__device__ inline unsigned short f2h(float x) {
    return __builtin_bit_cast(unsigned short, (_Float16)x);
}
__device__ inline f32x16 zero16() {
    f32x16 v;
    #pragma unroll
    for (int i = 0; i < 16; ++i) v[i] = 0.0f;
    return v;
}

// ---------------------------------------------------------------------------
__global__ void precompute_Bb(const float* __restrict__ base_cb,
                              const float* __restrict__ cp_w,
                              float* __restrict__ Bb) {
    const int mk = blockIdx.x;
    const int m  = mk >> 8;
    const int d  = threadIdx.x;
    const float* cb = base_cb + (size_t)mk * D_;
    const float* wc = cp_w + ((size_t)(m * D_ + d)) * (2 * D_) + D_;
    double a0 = 0, a1 = 0, a2 = 0, a3 = 0;
    #pragma unroll
    for (int dp = 0; dp < D_; dp += 4) {
        a0 += (double)(cb[dp + 0] * wc[dp + 0]);
        a1 += (double)(cb[dp + 1] * wc[dp + 1]);
        a2 += (double)(cb[dp + 2] * wc[dp + 2]);
        a3 += (double)(cb[dp + 3] * wc[dp + 3]);
    }
    Bb[(size_t)mk * D_ + d] = (float)((a0 + a1) + (a2 + a3));
}

// ---------------------------------------------------------------------------
// Pack weights (single f16) into wave-coalesced fragment order.
// w1pk index: ((((bi*8 + jblk)*8 + kt)*32 + j32)*2 + sel)*8 + e
//   source:   w1[bi][ j = jblk*32+j32 ][ d = kt*16 + sel*8 + e ]
// w2pk index: ((((bi*4 + dblk)*16 + s)*32 + d32)*2 + sel)*8 + e
//   source:   w2[bi][ d = dblk*32+d32 ][ h = s*16 + sel*8 + e ]
// ---------------------------------------------------------------------------
__global__ void convert_w(const float* __restrict__ w1,
                          const float* __restrict__ w2,
                          unsigned short* __restrict__ w1pk,
                          unsigned short* __restrict__ w2pk) {
    const int i = blockIdx.x * blockDim.x + threadIdx.x;  // 0..262143
    {
        const int e    = i & 7;
        const int sel  = (i >> 3) & 1;
        const int j32  = (i >> 4) & 31;
        const int kt   = (i >> 9) & 7;
        const int jblk = (i >> 12) & 7;
        const int bi   = i >> 15;
        const int j = jblk * 32 + j32;
        const int d = kt * 16 + sel * 8 + e;
        w1pk[i] = f2h(w1[((size_t)(bi * H_ + j)) * D_ + d]);
    }
    {
        const int e    = i & 7;
        const int sel  = (i >> 3) & 1;
        const int d32  = (i >> 4) & 31;
        const int s    = (i >> 9) & 15;
        const int dblk = (i >> 13) & 3;
        const int bi   = i >> 15;
        const int d = dblk * 32 + d32;
        const int hc = s * 16 + sel * 8 + e;
        w2pk[i] = f2h(w2[((size_t)(bi * D_ + d)) * H_ + hc]);
    }
}

__global__ void init_state(float* __restrict__ xhat, float* __restrict__ Ag) {
    const int i = blockIdx.x * blockDim.x + threadIdx.x;
    xhat[i] = 0.0f;
    Ag[i] = 0.0f;
}

// ---------------------------------------------------------------------------
// dist kernel: block (n, kt) -> fast dists for 32 codewords. 1-pass f16.
// ---------------------------------------------------------------------------
__launch_bounds__(256, 4)
__global__ void dist_kernel(const int m,
                            const float* __restrict__ z,
                            const float* __restrict__ cp_b,
                            const float* __restrict__ xhat,
                            const float* __restrict__ Ag,
                            const float* __restrict__ Bb,
                            const unsigned short* __restrict__ w1pk,
                            const unsigned short* __restrict__ w2pk,
                            const float* __restrict__ b1,
                            const float* __restrict__ b2,
                            float* __restrict__ gdist) {
    __shared__ alignas(16) unsigned short sCh[KT_][CHPAD];
    __shared__ alignas(16) unsigned short sHh[KT_][HPAD];
    __shared__ float sA[D_], sr[D_], scb[D_];

    const int bid  = blockIdx.x;
    const int n    = bid >> 3;
    const int k0   = (bid & 7) * KT_;
    const int t    = threadIdx.x;
    const int wid  = t >> 6;
    const int lane = t & 63;
    const int l31  = lane & 31;
    const int koff = (lane >> 5) * 8;
    const int loff = (l31 * 2 + (lane >> 5)) * 8;   // coalesced lane offset

    if (t < D_) {
        sA[t]  = Ag[(size_t)n * D_ + t];
        sr[t]  = z[(size_t)n * D_ + t] - xhat[(size_t)n * D_ + t];
        scb[t] = cp_b[m * D_ + t];
    }
    __syncthreads();

    // ---- C init: C = (A + Bb) + cp_b, single f16 ----
    {
        const int row  = t >> 3;
        const int dblk = (t & 7) * 16;
        const f32x4* bb4 = (const f32x4*)(Bb + ((size_t)(m * K_ + k0 + row)) * D_ + dblk);
        #pragma unroll
        for (int g = 0; g < 2; ++g) {
            const f32x4 v0 = bb4[g * 2];
            const f32x4 v1 = bb4[g * 2 + 1];
            short8 hs;
            #pragma unroll
            for (int x = 0; x < 8; ++x) {
                const int d = dblk + g * 8 + x;
                const float bv = (x < 4) ? v0[x] : v1[x - 4];
                hs[x] = (short)f2h((sA[d] + bv) + scb[d]);
            }
            *(short8*)&sCh[row][dblk + g * 8] = hs;
        }
    }
    __syncthreads();

    for (int i = 0; i < NB_; ++i) {
        const int bi = m * NB_ + i;

        // ================= GEMM1: h = relu(C @ W1^T + b1) ==================
        {
            const int j0 = wid * 32 + l31;
            const int j1 = j0 + 128;
            const unsigned short* pA = w1pk + ((size_t)(bi * 8 + wid) * 8) * 512 + loff;
            const unsigned short* pB = w1pk + ((size_t)(bi * 8 + wid + 4) * 8) * 512 + loff;

            half8 wA[8], wB[8];
            #pragma unroll
            for (int kt = 0; kt < 8; ++kt) wA[kt] = *(const half8*)(pA + kt * 512);
            #pragma unroll
            for (int kt = 0; kt < 8; ++kt) wB[kt] = *(const half8*)(pB + kt * 512);

            f32x16 accA = zero16(), accB = zero16();
            #pragma unroll
            for (int kt = 0; kt < 8; ++kt) {
                half8 ah = *(const half8*)&sCh[l31][kt * 16 + koff];
                accA = __builtin_amdgcn_mfma_f32_32x32x16_f16(ah, wA[kt], accA, 0, 0, 0);
                accB = __builtin_amdgcn_mfma_f32_32x32x16_f16(ah, wB[kt], accB, 0, 0, 0);
            }
            const float b1A = b1[(size_t)bi * H_ + j0];
            const float b1B = b1[(size_t)bi * H_ + j1];
            #pragma unroll
            for (int reg = 0; reg < 16; ++reg) {
                const int krow = (reg & 3) + 8 * (reg >> 2) + 4 * (lane >> 5);
                sHh[krow][j0] = f2h(fmaxf(accA[reg] + b1A, 0.0f));
                sHh[krow][j1] = f2h(fmaxf(accB[reg] + b1B, 0.0f));
            }
        }
        __syncthreads();

        // ================= GEMM2: C = (C + h @ W2^T) + b2 ==================
        {
            const int d = wid * 32 + l31;
            const unsigned short* pd = w2pk + ((size_t)(bi * 4 + wid) * 16) * 512 + loff;

            half8 wv[16];
            #pragma unroll
            for (int s = 0; s < 16; ++s) wv[s] = *(const half8*)(pd + s * 512);

            f32x16 acc0 = zero16(), acc1 = zero16();
            #pragma unroll
            for (int s = 0; s < 8; ++s) {
                half8 h0 = *(const half8*)&sHh[l31][s * 16 + koff];
                half8 h1 = *(const half8*)&sHh[l31][(s + 8) * 16 + koff];
                acc0 = __builtin_amdgcn_mfma_f32_32x32x16_f16(h0, wv[s], acc0, 0, 0, 0);
                acc1 = __builtin_amdgcn_mfma_f32_32x32x16_f16(h1, wv[s + 8], acc1, 0, 0, 0);
            }
            const float b2v = b2[(size_t)bi * D_ + d];
            #pragma unroll
            for (int reg = 0; reg < 16; ++reg) {
                const int krow = (reg & 3) + 8 * (reg >> 2) + 4 * (lane >> 5);
                const float cv = (s2f(sCh[krow][d]) + (acc0[reg] + acc1[reg])) + b2v;
                sCh[krow][d] = f2h(cv);
            }
        }
        __syncthreads();
    }

    // ---- fast dists ----
    if (t < 128) {
        const int row = t >> 2, seg = t & 3;
        float qa = 0.f;
        #pragma unroll
        for (int dd = 0; dd < 32; ++dd) {
            const int d = seg * 32 + dd;
            const float e = sr[d] - s2f(sCh[row][d]);
            qa = fmaf(e, e, qa);
        }
        qa += __shfl_xor(qa, 1);
        qa += __shfl_xor(qa, 2);
        if (seg == 0) gdist[(size_t)n * K_ + k0 + row] = qa;
    }
}

// ---------------------------------------------------------------------------
// refine kernel: per n — argmin + exact f64 refinement + outputs + state.
// ---------------------------------------------------------------------------
__launch_bounds__(256, 4)
__global__ void refine_kernel(const int m,
                              const float* __restrict__ z,
                              const float* __restrict__ cp_w,
                              const float* __restrict__ cp_b,
                              const float* __restrict__ w1,
                              const float* __restrict__ b1,
                              const float* __restrict__ w2,
                              const float* __restrict__ b2,
                              const float* __restrict__ Bb,
                              const float* __restrict__ gdist,
                              float* __restrict__ xhat,
                              float* __restrict__ Ag,
                              float* __restrict__ out0,
                              float* __restrict__ out1,
                              float* __restrict__ out2,
                              float* __restrict__ out3) {
    __shared__ float sxhat[D_], sA[D_], sr[D_], scb[D_], scsel[D_], sE[D_];
    __shared__ float shrow[H_];
    __shared__ float sdist[K_];
    __shared__ int   sflag[K_];
    __shared__ double sdd[2];
    __shared__ float smin, sbest;
    __shared__ int   sbidx, supd;

    const int n = blockIdx.x;
    const int t = threadIdx.x;

    if (t < D_) {
        const float xh = xhat[(size_t)n * D_ + t];
        sxhat[t] = xh;
        sA[t]    = Ag[(size_t)n * D_ + t];
        scb[t]   = cp_b[m * D_ + t];
        const float zv = z[(size_t)n * D_ + t];
        const float rv = zv - xh;
        sr[t] = rv;
        out2[((size_t)m * N_ + n) * D_ + t] = rv;
    }
    sdist[t] = gdist[(size_t)n * K_ + t];
    __syncthreads();

    if (t < 64) {
        float bv = 1e30f; int bx = 0;
        #pragma unroll
        for (int u = 0; u < 4; ++u) {
            const int idx = t * 4 + u;
            const float v = sdist[idx];
            if (v < bv) { bv = v; bx = idx; }
        }
        #pragma unroll
        for (int s = 1; s < 64; s <<= 1) {
            const float ov = __shfl_xor(bv, s);
            const int   ox = __shfl_xor(bx, s);
            if (ov < bv || (ov == bv && ox < bx)) { bv = ov; bx = ox; }
        }
        if (t == 0) smin = bv;
    }
    __syncthreads();
    sflag[t] = (sdist[t] <= smin + EPS_) ? 1 : 0;
    if (t == 0) { sbest = 1e30f; sbidx = 0; }
    __syncthreads();

    for (int k = 0; k < K_; ++k) {
        if (!sflag[k]) continue;
        if (t < D_)
            sE[t] = (sA[t] + Bb[((size_t)(m * K_ + k)) * D_ + t]) + scb[t];
        __syncthreads();
        for (int i = 0; i < NB_; ++i) {
            const int bi = m * NB_ + i;
            {
                const f32x4* wp = (const f32x4*)(w1 + ((size_t)bi * H_ + t) * D_);
                double h0 = 0, h1 = 0, h2 = 0, h3 = 0;
                #pragma unroll 8
                for (int u = 0; u < 32; ++u) {
                    f32x4 wv = wp[u];
                    h0 += (double)(sE[u * 4 + 0] * wv[0]);
                    h1 += (double)(sE[u * 4 + 1] * wv[1]);
                    h2 += (double)(sE[u * 4 + 2] * wv[2]);
                    h3 += (double)(sE[u * 4 + 3] * wv[3]);
                }
                const float hv = (float)((h0 + h1) + (h2 + h3)) + b1[(size_t)bi * H_ + t];
                shrow[t] = fmaxf(hv, 0.0f);
            }
            __syncthreads();
            if (t < D_) {
                const f32x4* wp = (const f32x4*)(w2 + ((size_t)bi * D_ + t) * H_);
                double s0 = 0, s1 = 0, s2 = 0, s3 = 0;
                #pragma unroll 8
                for (int u = 0; u < 64; ++u) {
                    f32x4 wv = wp[u];
                    s0 += (double)(shrow[u * 4 + 0] * wv[0]);
                    s1 += (double)(shrow[u * 4 + 1] * wv[1]);
                    s2 += (double)(shrow[u * 4 + 2] * wv[2]);
                    s3 += (double)(shrow[u * 4 + 3] * wv[3]);
                }
                sE[t] = (sE[t] + (float)((s0 + s1) + (s2 + s3))) + b2[(size_t)bi * D_ + t];
            }
            __syncthreads();
        }
        {
            double dp = 0.0;
            if (t < D_) {
                const float e = sr[t] - sE[t];
                const float e2 = e * e;
                dp = (double)e2;
                #pragma unroll
                for (int s = 1; s < 64; s <<= 1) dp += __shfl_xor(dp, s);
                if ((t & 63) == 0) sdd[t >> 6] = dp;
            }
        }
        __syncthreads();
        if (t == 0) {
            const float df = (float)(sdd[0] + sdd[1]);
            if (df < sbest) { sbest = df; sbidx = k; supd = 1; }
            else supd = 0;
        }
        __syncthreads();
        if (supd && t < D_) scsel[t] = sE[t];
        __syncthreads();
    }

    if (t == 0) out1[(size_t)n * M_ + m] = (float)sbidx;

    if (t < D_) {
        const float cs = scsel[t];
        out3[((size_t)m * N_ + n) * D_ + t] = cs;
        const float xnew = sxhat[t] + cs;
        xhat[(size_t)n * D_ + t] = xnew;
        sxhat[t] = xnew;
        if (m == M_ - 1) {
            const float zv = z[(size_t)n * D_ + t];
            out0[(size_t)n * D_ + t] = zv + (xnew - zv);
        }
    }
    __syncthreads();

    if (m < M_ - 1 && t < D_) {
        const f32x4* wp = (const f32x4*)(cp_w + ((size_t)((m + 1) * D_ + t)) * (2 * D_));
        double a0 = 0, a1 = 0, a2 = 0, a3 = 0;
        #pragma unroll 8
        for (int u = 0; u < 32; ++u) {
            f32x4 wv = wp[u];
            a0 += (double)(sxhat[u * 4 + 0] * wv[0]);
            a1 += (double)(sxhat[u * 4 + 1] * wv[1]);
            a2 += (double)(sxhat[u * 4 + 2] * wv[2]);
            a3 += (double)(sxhat[u * 4 + 3] * wv[3]);
        }
        Ag[(size_t)n * D_ + t] = (float)((a0 + a1) + (a2 + a3));
    }
}

extern "C" void kernel_launch(void* const* d_in, const int* in_sizes, int n_in,
                              void* d_out, int out_size, void* d_ws, size_t ws_size,
                              hipStream_t stream) {
    const float* z       = (const float*)d_in[0];
    const float* base_cb = (const float*)d_in[1];
    const float* cp_w    = (const float*)d_in[2];
    const float* cp_b    = (const float*)d_in[3];
    const float* w1      = (const float*)d_in[4];
    const float* b1      = (const float*)d_in[5];
    const float* w2      = (const float*)d_in[6];
    const float* b2      = (const float*)d_in[7];

    float* out  = (float*)d_out;
    float* out0 = out;
    float* out1 = out0 + (size_t)N_ * D_;
    float* out2 = out1 + (size_t)N_ * M_;
    float* out3 = out2 + (size_t)M_ * N_ * D_;

    char* ws = (char*)d_ws;
    float*          Bb    = (float*)(ws + 0);
    unsigned short* w1pk  = (unsigned short*)(ws + 524288);
    unsigned short* w2pk  = (unsigned short*)(ws + 1048576);
    float*          xhat  = (float*)(ws + 1572864);
    float*          Ag    = (float*)(ws + 2097152);
    float*          gdist = (float*)(ws + 2621440);

    hipLaunchKernelGGL(precompute_Bb, dim3(M_ * K_), dim3(D_), 0, stream,
                       base_cb, cp_w, Bb);
    hipLaunchKernelGGL(convert_w, dim3(1024), dim3(256), 0, stream,
                       w1, w2, w1pk, w2pk);
    hipLaunchKernelGGL(init_state, dim3(512), dim3(256), 0, stream, xhat, Ag);

    for (int m = 0; m < M_; ++m) {
        hipLaunchKernelGGL(dist_kernel, dim3(N_ * 8), dim3(256), 0, stream,
                           m, z, cp_b, xhat, Ag, Bb,
                           w1pk, w2pk, b1, b2, gdist);
        hipLaunchKernelGGL(refine_kernel, dim3(N_), dim3(256), 0, stream,
                           m, z, cp_w, cp_b, w1, b1, w2, b2, Bb, gdist,
                           xhat, Ag, out0, out1, out2, out3);
    }
}

// Round 11
// 1434.838 us; speedup vs baseline: 1.6321x; 1.6321x over previous
//
#include <hip/hip_runtime.h>

#define N_ 1024
#define D_ 128
#define K_ 256
#define M_ 4
#define H_ 256
#define NB_ 2
#define KT_ 32
#define EPS_ 0.12f
#define CMAX_ 8
#define CHPAD 136
#define HPAD  264

typedef _Float16 half8 __attribute__((ext_vector_type(8)));
typedef __attribute__((ext_vector_type(8))) short short8;
typedef __attribute__((ext_vector_type(4))) float f32x4;
typedef __attribute__((ext_vector_type(16))) float f32x16;

__device__ inline float s2f(unsigned short s) {
    return (float)__builtin_bit_cast(_Float16, s);
}
__device__ inline unsigned short f2h(float x) {
    return __builtin_bit_cast(unsigned short, (_Float16)x);
}
__device__ inline void split2h(float x, unsigned short& hi, unsigned short& lo) {
    _Float16 h = (_Float16)x;
    _Float16 l = (_Float16)(x - (float)h);
    hi = __builtin_bit_cast(unsigned short, h);
    lo = __builtin_bit_cast(unsigned short, l);
}
__device__ inline f32x16 zero16() {
    f32x16 v;
    #pragma unroll
    for (int i = 0; i < 16; ++i) v[i] = 0.0f;
    return v;
}

// ---------------------------------------------------------------------------
__global__ void precompute_Bb(const float* __restrict__ base_cb,
                              const float* __restrict__ cp_w,
                              float* __restrict__ Bb) {
    const int mk = blockIdx.x;
    const int m  = mk >> 8;
    const int d  = threadIdx.x;
    const float* cb = base_cb + (size_t)mk * D_;
    const float* wc = cp_w + ((size_t)(m * D_ + d)) * (2 * D_) + D_;
    double a0 = 0, a1 = 0, a2 = 0, a3 = 0;
    #pragma unroll
    for (int dp = 0; dp < D_; dp += 4) {
        a0 += (double)(cb[dp + 0] * wc[dp + 0]);
        a1 += (double)(cb[dp + 1] * wc[dp + 1]);
        a2 += (double)(cb[dp + 2] * wc[dp + 2]);
        a3 += (double)(cb[dp + 3] * wc[dp + 3]);
    }
    Bb[(size_t)mk * D_ + d] = (float)((a0 + a1) + (a2 + a3));
}

// ---------------------------------------------------------------------------
// Pack weights (f16 hi/lo) into wave-coalesced fragment order (as R9).
// ---------------------------------------------------------------------------
__global__ void convert_w(const float* __restrict__ w1,
                          const float* __restrict__ w2,
                          unsigned short* __restrict__ w1h,
                          unsigned short* __restrict__ w1l,
                          unsigned short* __restrict__ w2h,
                          unsigned short* __restrict__ w2l) {
    const int i = blockIdx.x * blockDim.x + threadIdx.x;  // 0..262143
    {
        const int e    = i & 7;
        const int sel  = (i >> 3) & 1;
        const int j32  = (i >> 4) & 31;
        const int kt   = (i >> 9) & 7;
        const int jblk = (i >> 12) & 7;
        const int bi   = i >> 15;
        const int j = jblk * 32 + j32;
        const int d = kt * 16 + sel * 8 + e;
        unsigned short h, l;
        split2h(w1[((size_t)(bi * H_ + j)) * D_ + d], h, l);
        w1h[i] = h; w1l[i] = l;
    }
    {
        const int e    = i & 7;
        const int sel  = (i >> 3) & 1;
        const int d32  = (i >> 4) & 31;
        const int s    = (i >> 9) & 15;
        const int dblk = (i >> 13) & 3;
        const int bi   = i >> 15;
        const int d = dblk * 32 + d32;
        const int hc = s * 16 + sel * 8 + e;
        unsigned short h, l;
        split2h(w2[((size_t)(bi * D_ + d)) * H_ + hc], h, l);
        w2h[i] = h; w2l[i] = l;
    }
}

__global__ void init_state(float* __restrict__ xhat, float* __restrict__ Ag) {
    const int i = blockIdx.x * blockDim.x + threadIdx.x;
    xhat[i] = 0.0f;
    Ag[i] = 0.0f;
}

// ---------------------------------------------------------------------------
// dist kernel: C fully split (3-pass GEMM1); h single f16 (2-pass GEMM2).
// ---------------------------------------------------------------------------
__launch_bounds__(256, 4)
__global__ void dist_kernel(const int m,
                            const float* __restrict__ z,
                            const float* __restrict__ cp_b,
                            const float* __restrict__ xhat,
                            const float* __restrict__ Ag,
                            const float* __restrict__ Bb,
                            const unsigned short* __restrict__ w1hpk,
                            const unsigned short* __restrict__ w1lpk,
                            const unsigned short* __restrict__ w2hpk,
                            const unsigned short* __restrict__ w2lpk,
                            const float* __restrict__ b1,
                            const float* __restrict__ b2,
                            float* __restrict__ gdist) {
    __shared__ alignas(16) unsigned short sChi[KT_][CHPAD];
    __shared__ alignas(16) unsigned short sClo[KT_][CHPAD];
    __shared__ alignas(16) unsigned short sHh[KT_][HPAD];
    __shared__ float sA[D_], sr[D_], scb[D_];

    const int bid  = blockIdx.x;
    const int n    = bid >> 3;
    const int k0   = (bid & 7) * KT_;
    const int t    = threadIdx.x;
    const int wid  = t >> 6;
    const int lane = t & 63;
    const int l31  = lane & 31;
    const int koff = (lane >> 5) * 8;
    const int loff = (l31 * 2 + (lane >> 5)) * 8;

    if (t < D_) {
        sA[t]  = Ag[(size_t)n * D_ + t];
        sr[t]  = z[(size_t)n * D_ + t] - xhat[(size_t)n * D_ + t];
        scb[t] = cp_b[m * D_ + t];
    }
    __syncthreads();

    // ---- C init: split f16 hi/lo ----
    {
        const int row  = t >> 3;
        const int dblk = (t & 7) * 16;
        const f32x4* bb4 = (const f32x4*)(Bb + ((size_t)(m * K_ + k0 + row)) * D_ + dblk);
        #pragma unroll
        for (int g = 0; g < 2; ++g) {
            const f32x4 v0 = bb4[g * 2];
            const f32x4 v1 = bb4[g * 2 + 1];
            short8 hs, ls;
            #pragma unroll
            for (int x = 0; x < 8; ++x) {
                const int d = dblk + g * 8 + x;
                const float bv = (x < 4) ? v0[x] : v1[x - 4];
                unsigned short ch, cl;
                split2h((sA[d] + bv) + scb[d], ch, cl);
                hs[x] = (short)ch;
                ls[x] = (short)cl;
            }
            *(short8*)&sChi[row][dblk + g * 8] = hs;
            *(short8*)&sClo[row][dblk + g * 8] = ls;
        }
    }
    __syncthreads();

    for (int i = 0; i < NB_; ++i) {
        const int bi = m * NB_ + i;

        // ======== GEMM1 (3-pass): h = relu(C @ W1^T + b1), h single f16 =====
        {
            const int j0 = wid * 32 + l31;
            const int j1 = j0 + 128;
            const unsigned short* pAh = w1hpk + ((size_t)(bi * 8 + wid) * 8) * 512 + loff;
            const unsigned short* pAl = w1lpk + ((size_t)(bi * 8 + wid) * 8) * 512 + loff;
            const unsigned short* pBh = w1hpk + ((size_t)(bi * 8 + wid + 4) * 8) * 512 + loff;
            const unsigned short* pBl = w1lpk + ((size_t)(bi * 8 + wid + 4) * 8) * 512 + loff;

            half8 wA[16], wB[16];
            #pragma unroll
            for (int kt = 0; kt < 8; ++kt) {
                wA[2 * kt]     = *(const half8*)(pAh + kt * 512);
                wA[2 * kt + 1] = *(const half8*)(pAl + kt * 512);
            }
            f32x16 acc = zero16();
            #pragma unroll
            for (int kt = 0; kt < 4; ++kt) {
                half8 ah = *(const half8*)&sChi[l31][kt * 16 + koff];
                half8 al = *(const half8*)&sClo[l31][kt * 16 + koff];
                acc = __builtin_amdgcn_mfma_f32_32x32x16_f16(ah, wA[2 * kt], acc, 0, 0, 0);
                acc = __builtin_amdgcn_mfma_f32_32x32x16_f16(ah, wA[2 * kt + 1], acc, 0, 0, 0);
                acc = __builtin_amdgcn_mfma_f32_32x32x16_f16(al, wA[2 * kt], acc, 0, 0, 0);
            }
            #pragma unroll
            for (int kt = 0; kt < 8; ++kt) {
                wB[2 * kt]     = *(const half8*)(pBh + kt * 512);
                wB[2 * kt + 1] = *(const half8*)(pBl + kt * 512);
            }
            #pragma unroll
            for (int kt = 4; kt < 8; ++kt) {
                half8 ah = *(const half8*)&sChi[l31][kt * 16 + koff];
                half8 al = *(const half8*)&sClo[l31][kt * 16 + koff];
                acc = __builtin_amdgcn_mfma_f32_32x32x16_f16(ah, wA[2 * kt], acc, 0, 0, 0);
                acc = __builtin_amdgcn_mfma_f32_32x32x16_f16(ah, wA[2 * kt + 1], acc, 0, 0, 0);
                acc = __builtin_amdgcn_mfma_f32_32x32x16_f16(al, wA[2 * kt], acc, 0, 0, 0);
            }
            {
                const float b1A = b1[(size_t)bi * H_ + j0];
                #pragma unroll
                for (int reg = 0; reg < 16; ++reg) {
                    const int krow = (reg & 3) + 8 * (reg >> 2) + 4 * (lane >> 5);
                    sHh[krow][j0] = f2h(fmaxf(acc[reg] + b1A, 0.0f));
                }
            }
            acc = zero16();
            #pragma unroll
            for (int kt = 0; kt < 8; ++kt) {
                half8 ah = *(const half8*)&sChi[l31][kt * 16 + koff];
                half8 al = *(const half8*)&sClo[l31][kt * 16 + koff];
                acc = __builtin_amdgcn_mfma_f32_32x32x16_f16(ah, wB[2 * kt], acc, 0, 0, 0);
                acc = __builtin_amdgcn_mfma_f32_32x32x16_f16(ah, wB[2 * kt + 1], acc, 0, 0, 0);
                acc = __builtin_amdgcn_mfma_f32_32x32x16_f16(al, wB[2 * kt], acc, 0, 0, 0);
            }
            {
                const float b1B = b1[(size_t)bi * H_ + j1];
                #pragma unroll
                for (int reg = 0; reg < 16; ++reg) {
                    const int krow = (reg & 3) + 8 * (reg >> 2) + 4 * (lane >> 5);
                    sHh[krow][j1] = f2h(fmaxf(acc[reg] + b1B, 0.0f));
                }
            }
        }
        __syncthreads();

        // ======== GEMM2 (2-pass): C = (C + h @ W2^T) + b2 ===================
        {
            const int d = wid * 32 + l31;
            const unsigned short* pdh = w2hpk + ((size_t)(bi * 4 + wid) * 16) * 512 + loff;
            const unsigned short* pdl = w2lpk + ((size_t)(bi * 4 + wid) * 16) * 512 + loff;

            half8 wh[8], wl[8];
            #pragma unroll
            for (int s = 0; s < 8; ++s) {
                wh[s] = *(const half8*)(pdh + s * 512);
                wl[s] = *(const half8*)(pdl + s * 512);
            }
            f32x16 acc0 = zero16(), acc1 = zero16();
            #pragma unroll
            for (int s = 0; s < 8; ++s) {
                half8 h0 = *(const half8*)&sHh[l31][s * 16 + koff];
                acc0 = __builtin_amdgcn_mfma_f32_32x32x16_f16(h0, wh[s], acc0, 0, 0, 0);
                acc0 = __builtin_amdgcn_mfma_f32_32x32x16_f16(h0, wl[s], acc0, 0, 0, 0);
            }
            #pragma unroll
            for (int s = 0; s < 8; ++s) {
                wh[s] = *(const half8*)(pdh + (s + 8) * 512);
                wl[s] = *(const half8*)(pdl + (s + 8) * 512);
            }
            #pragma unroll
            for (int s = 0; s < 8; ++s) {
                half8 h1 = *(const half8*)&sHh[l31][(s + 8) * 16 + koff];
                acc1 = __builtin_amdgcn_mfma_f32_32x32x16_f16(h1, wh[s], acc1, 0, 0, 0);
                acc1 = __builtin_amdgcn_mfma_f32_32x32x16_f16(h1, wl[s], acc1, 0, 0, 0);
            }
            const float b2v = b2[(size_t)bi * D_ + d];
            #pragma unroll
            for (int reg = 0; reg < 16; ++reg) {
                const int krow = (reg & 3) + 8 * (reg >> 2) + 4 * (lane >> 5);
                const float cvo = s2f(sChi[krow][d]) + s2f(sClo[krow][d]);
                const float cv  = (cvo + (acc0[reg] + acc1[reg])) + b2v;
                unsigned short ch, cl;
                split2h(cv, ch, cl);
                sChi[krow][d] = ch;
                sClo[krow][d] = cl;
            }
        }
        __syncthreads();
    }

    // ---- fast dists ----
    if (t < 128) {
        const int row = t >> 2, seg = t & 3;
        float qa = 0.f;
        #pragma unroll
        for (int dd = 0; dd < 32; ++dd) {
            const int d = seg * 32 + dd;
            const float cv = s2f(sChi[row][d]) + s2f(sClo[row][d]);
            const float e = sr[d] - cv;
            qa = fmaf(e, e, qa);
        }
        qa += __shfl_xor(qa, 1);
        qa += __shfl_xor(qa, 2);
        if (seg == 0) gdist[(size_t)n * K_ + k0 + row] = qa;
    }
}

// ---------------------------------------------------------------------------
// compact: per n, find min fast-dist and collect candidates (increasing k).
// ---------------------------------------------------------------------------
__global__ void compact_kernel(const float* __restrict__ gdist,
                               unsigned char* __restrict__ cands,
                               int* __restrict__ ccnt) {
    __shared__ float sdist[K_];
    __shared__ float swmin[4];
    __shared__ float smin;
    const int n = blockIdx.x, t = threadIdx.x;
    const float v = gdist[(size_t)n * K_ + t];
    sdist[t] = v;
    float bv = v;
    #pragma unroll
    for (int s = 1; s < 64; s <<= 1) bv = fminf(bv, __shfl_xor(bv, s));
    if ((t & 63) == 0) swmin[t >> 6] = bv;
    __syncthreads();
    if (t == 0) {
        smin = fminf(fminf(swmin[0], swmin[1]), fminf(swmin[2], swmin[3]));
        const float thr = smin + EPS_;
        int cnt = 0;
        for (int k = 0; k < K_; ++k)
            if (sdist[k] <= thr) cands[(size_t)n * K_ + (cnt++)] = (unsigned char)k;
        ccnt[n] = cnt;
    }
}

// ---------------------------------------------------------------------------
// eval: grid (N, CMAX). Exact f64 dist for candidate ranks (parallel).
// Skipped when cnt==1. Writes exact dist into edist[n*K + rank].
// ---------------------------------------------------------------------------
__launch_bounds__(256, 4)
__global__ void eval_kernel(const int m,
                            const float* __restrict__ z,
                            const float* __restrict__ cp_b,
                            const float* __restrict__ w1,
                            const float* __restrict__ b1,
                            const float* __restrict__ w2,
                            const float* __restrict__ b2,
                            const float* __restrict__ Bb,
                            const float* __restrict__ xhat,
                            const float* __restrict__ Ag,
                            const unsigned char* __restrict__ cands,
                            const int* __restrict__ ccnt,
                            float* __restrict__ edist) {
    const int n = blockIdx.x;
    const int cnt = ccnt[n];
    if (cnt <= 1) return;

    __shared__ float sA[D_], sr[D_], scb[D_], sE[D_];
    __shared__ float shrow[H_];
    __shared__ double sdd[2];
    const int t = threadIdx.x;

    if (t < D_) {
        sA[t]  = Ag[(size_t)n * D_ + t];
        sr[t]  = z[(size_t)n * D_ + t] - xhat[(size_t)n * D_ + t];
        scb[t] = cp_b[m * D_ + t];
    }
    __syncthreads();

    for (int rank = blockIdx.y; rank < cnt; rank += CMAX_) {
        const int k = cands[(size_t)n * K_ + rank];
        if (t < D_)
            sE[t] = (sA[t] + Bb[((size_t)(m * K_ + k)) * D_ + t]) + scb[t];
        __syncthreads();
        for (int i = 0; i < NB_; ++i) {
            const int bi = m * NB_ + i;
            {
                const f32x4* wp = (const f32x4*)(w1 + ((size_t)bi * H_ + t) * D_);
                double h0 = 0, h1 = 0, h2 = 0, h3 = 0;
                #pragma unroll 8
                for (int u = 0; u < 32; ++u) {
                    f32x4 wv = wp[u];
                    h0 += (double)(sE[u * 4 + 0] * wv[0]);
                    h1 += (double)(sE[u * 4 + 1] * wv[1]);
                    h2 += (double)(sE[u * 4 + 2] * wv[2]);
                    h3 += (double)(sE[u * 4 + 3] * wv[3]);
                }
                const float hv = (float)((h0 + h1) + (h2 + h3)) + b1[(size_t)bi * H_ + t];
                shrow[t] = fmaxf(hv, 0.0f);
            }
            __syncthreads();
            if (t < D_) {
                const f32x4* wp = (const f32x4*)(w2 + ((size_t)bi * D_ + t) * H_);
                double s0 = 0, s1 = 0, s2 = 0, s3 = 0;
                #pragma unroll 8
                for (int u = 0; u < 64; ++u) {
                    f32x4 wv = wp[u];
                    s0 += (double)(shrow[u * 4 + 0] * wv[0]);
                    s1 += (double)(shrow[u * 4 + 1] * wv[1]);
                    s2 += (double)(shrow[u * 4 + 2] * wv[2]);
                    s3 += (double)(shrow[u * 4 + 3] * wv[3]);
                }
                sE[t] = (sE[t] + (float)((s0 + s1) + (s2 + s3))) + b2[(size_t)bi * D_ + t];
            }
            __syncthreads();
        }
        {
            double dp = 0.0;
            if (t < D_) {
                const float e = sr[t] - sE[t];
                const float e2 = e * e;
                dp = (double)e2;
                #pragma unroll
                for (int s = 1; s < 64; s <<= 1) dp += __shfl_xor(dp, s);
                if ((t & 63) == 0) sdd[t >> 6] = dp;
            }
        }
        __syncthreads();
        if (t == 0) edist[(size_t)n * K_ + rank] = (float)(sdd[0] + sdd[1]);
        __syncthreads();
    }
}

// ---------------------------------------------------------------------------
// update: pick exact argmin among candidates (k-order tie-break), recompute
// winner row exactly, write outputs, update xhat and A.
// ---------------------------------------------------------------------------
__launch_bounds__(256, 4)
__global__ void update_kernel(const int m,
                              const float* __restrict__ z,
                              const float* __restrict__ cp_w,
                              const float* __restrict__ cp_b,
                              const float* __restrict__ w1,
                              const float* __restrict__ b1,
                              const float* __restrict__ w2,
                              const float* __restrict__ b2,
                              const float* __restrict__ Bb,
                              const unsigned char* __restrict__ cands,
                              const int* __restrict__ ccnt,
                              const float* __restrict__ edist,
                              float* __restrict__ xhat,
                              float* __restrict__ Ag,
                              float* __restrict__ out0,
                              float* __restrict__ out1,
                              float* __restrict__ out2,
                              float* __restrict__ out3) {
    __shared__ float sxhat[D_], sA[D_], sr[D_], scb[D_], sE[D_];
    __shared__ float shrow[H_];
    __shared__ int scode;

    const int n = blockIdx.x;
    const int t = threadIdx.x;

    if (t < D_) {
        const float xh = xhat[(size_t)n * D_ + t];
        sxhat[t] = xh;
        sA[t]    = Ag[(size_t)n * D_ + t];
        scb[t]   = cp_b[m * D_ + t];
        const float rv = z[(size_t)n * D_ + t] - xh;
        sr[t] = rv;
        out2[((size_t)m * N_ + n) * D_ + t] = rv;
    }
    if (t == 0) {
        const int cnt = ccnt[n];
        int code = cands[(size_t)n * K_];
        if (cnt > 1) {
            float best = edist[(size_t)n * K_];
            for (int r = 1; r < cnt; ++r) {
                const float v = edist[(size_t)n * K_ + r];
                if (v < best) { best = v; code = cands[(size_t)n * K_ + r]; }
            }
        }
        scode = code;
        out1[(size_t)n * M_ + m] = (float)code;
    }
    __syncthreads();

    const int k = scode;
    if (t < D_)
        sE[t] = (sA[t] + Bb[((size_t)(m * K_ + k)) * D_ + t]) + scb[t];
    __syncthreads();
    for (int i = 0; i < NB_; ++i) {
        const int bi = m * NB_ + i;
        {
            const f32x4* wp = (const f32x4*)(w1 + ((size_t)bi * H_ + t) * D_);
            double h0 = 0, h1 = 0, h2 = 0, h3 = 0;
            #pragma unroll 8
            for (int u = 0; u < 32; ++u) {
                f32x4 wv = wp[u];
                h0 += (double)(sE[u * 4 + 0] * wv[0]);
                h1 += (double)(sE[u * 4 + 1] * wv[1]);
                h2 += (double)(sE[u * 4 + 2] * wv[2]);
                h3 += (double)(sE[u * 4 + 3] * wv[3]);
            }
            const float hv = (float)((h0 + h1) + (h2 + h3)) + b1[(size_t)bi * H_ + t];
            shrow[t] = fmaxf(hv, 0.0f);
        }
        __syncthreads();
        if (t < D_) {
            const f32x4* wp = (const f32x4*)(w2 + ((size_t)bi * D_ + t) * H_);
            double s0 = 0, s1 = 0, s2 = 0, s3 = 0;
            #pragma unroll 8
            for (int u = 0; u < 64; ++u) {
                f32x4 wv = wp[u];
                s0 += (double)(shrow[u * 4 + 0] * wv[0]);
                s1 += (double)(shrow[u * 4 + 1] * wv[1]);
                s2 += (double)(shrow[u * 4 + 2] * wv[2]);
                s3 += (double)(shrow[u * 4 + 3] * wv[3]);
            }
            sE[t] = (sE[t] + (float)((s0 + s1) + (s2 + s3))) + b2[(size_t)bi * D_ + t];
        }
        __syncthreads();
    }

    if (t < D_) {
        const float cs = sE[t];
        out3[((size_t)m * N_ + n) * D_ + t] = cs;
        const float xnew = sxhat[t] + cs;
        xhat[(size_t)n * D_ + t] = xnew;
        sxhat[t] = xnew;
        if (m == M_ - 1) {
            const float zv = z[(size_t)n * D_ + t];
            out0[(size_t)n * D_ + t] = zv + (xnew - zv);
        }
    }
    __syncthreads();

    if (m < M_ - 1 && t < D_) {
        const f32x4* wp = (const f32x4*)(cp_w + ((size_t)((m + 1) * D_ + t)) * (2 * D_));
        double a0 = 0, a1 = 0, a2 = 0, a3 = 0;
        #pragma unroll 8
        for (int u = 0; u < 32; ++u) {
            f32x4 wv = wp[u];
            a0 += (double)(sxhat[u * 4 + 0] * wv[0]);
            a1 += (double)(sxhat[u * 4 + 1] * wv[1]);
            a2 += (double)(sxhat[u * 4 + 2] * wv[2]);
            a3 += (double)(sxhat[u * 4 + 3] * wv[3]);
        }
        Ag[(size_t)n * D_ + t] = (float)((a0 + a1) + (a2 + a3));
    }
}

extern "C" void kernel_launch(void* const* d_in, const int* in_sizes, int n_in,
                              void* d_out, int out_size, void* d_ws, size_t ws_size,
                              hipStream_t stream) {
    const float* z       = (const float*)d_in[0];
    const float* base_cb = (const float*)d_in[1];
    const float* cp_w    = (const float*)d_in[2];
    const float* cp_b    = (const float*)d_in[3];
    const float* w1      = (const float*)d_in[4];
    const float* b1      = (const float*)d_in[5];
    const float* w2      = (const float*)d_in[6];
    const float* b2      = (const float*)d_in[7];

    float* out  = (float*)d_out;
    float* out0 = out;
    float* out1 = out0 + (size_t)N_ * D_;
    float* out2 = out1 + (size_t)N_ * M_;
    float* out3 = out2 + (size_t)M_ * N_ * D_;

    char* ws = (char*)d_ws;
    float*          Bb    = (float*)(ws + 0);
    unsigned short* w1hpk = (unsigned short*)(ws + 524288);
    unsigned short* w1lpk = (unsigned short*)(ws + 1048576);
    unsigned short* w2hpk = (unsigned short*)(ws + 1572864);
    unsigned short* w2lpk = (unsigned short*)(ws + 2097152);
    float*          xhat  = (float*)(ws + 2621440);
    float*          Ag    = (float*)(ws + 3145728);
    float*          gdist = (float*)(ws + 3670016);   // fast dists; reused for exact dists by rank
    unsigned char*  cands = (unsigned char*)(ws + 4718592);
    int*            ccnt  = (int*)(ws + 4980736);

    hipLaunchKernelGGL(precompute_Bb, dim3(M_ * K_), dim3(D_), 0, stream,
                       base_cb, cp_w, Bb);
    hipLaunchKernelGGL(convert_w, dim3(1024), dim3(256), 0, stream,
                       w1, w2, w1hpk, w1lpk, w2hpk, w2lpk);
    hipLaunchKernelGGL(init_state, dim3(512), dim3(256), 0, stream, xhat, Ag);

    for (int m = 0; m < M_; ++m) {
        hipLaunchKernelGGL(dist_kernel, dim3(N_ * 8), dim3(256), 0, stream,
                           m, z, cp_b, xhat, Ag, Bb,
                           w1hpk, w1lpk, w2hpk, w2lpk, b1, b2, gdist);
        hipLaunchKernelGGL(compact_kernel, dim3(N_), dim3(K_), 0, stream,
                           gdist, cands, ccnt);
        hipLaunchKernelGGL(eval_kernel, dim3(N_, CMAX_), dim3(256), 0, stream,
                           m, z, cp_b, w1, b1, w2, b2, Bb, xhat, Ag,
                           cands, ccnt, gdist);
        hipLaunchKernelGGL(update_kernel, dim3(N_), dim3(256), 0, stream,
                           m, z, cp_w, cp_b, w1, b1, w2, b2, Bb,
                           cands, ccnt, gdist, xhat, Ag,
                           out0, out1, out2, out3);
    }
}

// Round 12
// 1183.185 us; speedup vs baseline: 1.9793x; 1.2127x over previous
//
#include <hip/hip_runtime.h>

#define N_ 1024
#define D_ 128
#define K_ 256
#define M_ 4
#define H_ 256
#define NB_ 2
#define KT_ 64
#define NTILE_ 4
#define EPS_ 0.12f
#define CHPAD 136   // u16 per C row
#define HHPAD 136   // u16 per half-H row

typedef _Float16 half8 __attribute__((ext_vector_type(8)));
typedef __attribute__((ext_vector_type(8))) short short8;
typedef __attribute__((ext_vector_type(4))) float f32x4;
typedef __attribute__((ext_vector_type(16))) float f32x16;

__device__ inline float s2f(unsigned short s) {
    return (float)__builtin_bit_cast(_Float16, s);
}
__device__ inline unsigned short f2h(float x) {
    return __builtin_bit_cast(unsigned short, (_Float16)x);
}
__device__ inline void split2h(float x, unsigned short& hi, unsigned short& lo) {
    _Float16 h = (_Float16)x;
    _Float16 l = (_Float16)(x - (float)h);
    hi = __builtin_bit_cast(unsigned short, h);
    lo = __builtin_bit_cast(unsigned short, l);
}
__device__ inline f32x16 zero16() {
    f32x16 v;
    #pragma unroll
    for (int i = 0; i < 16; ++i) v[i] = 0.0f;
    return v;
}

// ---------------------------------------------------------------------------
__global__ void precompute_Bb(const float* __restrict__ base_cb,
                              const float* __restrict__ cp_w,
                              float* __restrict__ Bb) {
    const int mk = blockIdx.x;
    const int m  = mk >> 8;
    const int d  = threadIdx.x;
    const float* cb = base_cb + (size_t)mk * D_;
    const float* wc = cp_w + ((size_t)(m * D_ + d)) * (2 * D_) + D_;
    double a0 = 0, a1 = 0, a2 = 0, a3 = 0;
    #pragma unroll
    for (int dp = 0; dp < D_; dp += 4) {
        a0 += (double)(cb[dp + 0] * wc[dp + 0]);
        a1 += (double)(cb[dp + 1] * wc[dp + 1]);
        a2 += (double)(cb[dp + 2] * wc[dp + 2]);
        a3 += (double)(cb[dp + 3] * wc[dp + 3]);
    }
    Bb[(size_t)mk * D_ + d] = (float)((a0 + a1) + (a2 + a3));
}

// ---------------------------------------------------------------------------
// Pack weights (f16 hi/lo) into wave-coalesced fragment order (as R9/R11).
// ---------------------------------------------------------------------------
__global__ void convert_w(const float* __restrict__ w1,
                          const float* __restrict__ w2,
                          unsigned short* __restrict__ w1h,
                          unsigned short* __restrict__ w1l,
                          unsigned short* __restrict__ w2h,
                          unsigned short* __restrict__ w2l) {
    const int i = blockIdx.x * blockDim.x + threadIdx.x;  // 0..262143
    {
        const int e    = i & 7;
        const int sel  = (i >> 3) & 1;
        const int j32  = (i >> 4) & 31;
        const int kt   = (i >> 9) & 7;
        const int jblk = (i >> 12) & 7;
        const int bi   = i >> 15;
        const int j = jblk * 32 + j32;
        const int d = kt * 16 + sel * 8 + e;
        unsigned short h, l;
        split2h(w1[((size_t)(bi * H_ + j)) * D_ + d], h, l);
        w1h[i] = h; w1l[i] = l;
    }
    {
        const int e    = i & 7;
        const int sel  = (i >> 3) & 1;
        const int d32  = (i >> 4) & 31;
        const int s    = (i >> 9) & 15;
        const int dblk = (i >> 13) & 3;
        const int bi   = i >> 15;
        const int d = dblk * 32 + d32;
        const int hc = s * 16 + sel * 8 + e;
        unsigned short h, l;
        split2h(w2[((size_t)(bi * D_ + d)) * H_ + hc], h, l);
        w2h[i] = h; w2l[i] = l;
    }
}

// ---------------------------------------------------------------------------
// mega kernel: one block per n; entire M-loop; LDS-resident state.
// Per m: 4 tiles of 64 codewords (fast f16-split MFMA dists) -> serial exact
// f64 refinement of near-min candidates -> outputs + x_hat/A update.
// ---------------------------------------------------------------------------
__launch_bounds__(256, 2)
__global__ void mega_kernel(const float* __restrict__ z,
                            const float* __restrict__ cp_w,
                            const float* __restrict__ cp_b,
                            const float* __restrict__ w1,
                            const float* __restrict__ b1,
                            const float* __restrict__ w2,
                            const float* __restrict__ b2,
                            const float* __restrict__ Bb,
                            const unsigned short* __restrict__ w1hpk,
                            const unsigned short* __restrict__ w1lpk,
                            const unsigned short* __restrict__ w2hpk,
                            const unsigned short* __restrict__ w2lpk,
                            float* __restrict__ out0,
                            float* __restrict__ out1,
                            float* __restrict__ out2,
                            float* __restrict__ out3) {
    __shared__ alignas(16) unsigned short sChi[KT_][CHPAD];
    __shared__ alignas(16) unsigned short sClo[KT_][CHPAD];
    __shared__ alignas(16) unsigned short sHh[KT_][HHPAD];
    __shared__ float sA[D_], sxhat[D_], sr[D_], scb[D_];
    __shared__ float sdist[K_];
    __shared__ float sE[D_], scsel[D_];
    __shared__ float shrow[H_];
    __shared__ double sdd[2];
    __shared__ float smin, sbest;
    __shared__ int   sbidx, supd;

    const int n    = blockIdx.x;
    const int t    = threadIdx.x;
    const int wid  = t >> 6;
    const int lane = t & 63;
    const int l31  = lane & 31;
    const int koff = (lane >> 5) * 8;
    const int loff = (l31 * 2 + (lane >> 5)) * 8;

    if (t < D_) { sxhat[t] = 0.0f; sA[t] = 0.0f; }
    __syncthreads();

    for (int m = 0; m < M_; ++m) {
        // ---- prologue: r, cp_b, residual output ----
        if (t < D_) {
            scb[t] = cp_b[m * D_ + t];
            const float rv = z[(size_t)n * D_ + t] - sxhat[t];
            sr[t] = rv;
            out2[((size_t)m * N_ + n) * D_ + t] = rv;
        }
        __syncthreads();

        // ================= fast path: 4 tiles of 64 codewords ==============
        for (int tile = 0; tile < NTILE_; ++tile) {
            const int k0 = tile * KT_;

            // ---- C init: C = (A + Bb) + cp_b, f16 hi/lo split ----
            {
                const int row = t >> 2;
                const int cb0 = (t & 3) * 32;
                const f32x4* bb4 = (const f32x4*)(Bb + ((size_t)(m * K_ + k0 + row)) * D_ + cb0);
                #pragma unroll
                for (int g = 0; g < 4; ++g) {
                    const f32x4 v0 = bb4[g * 2];
                    const f32x4 v1 = bb4[g * 2 + 1];
                    short8 hs, ls;
                    #pragma unroll
                    for (int x = 0; x < 8; ++x) {
                        const int d = cb0 + g * 8 + x;
                        const float bv = (x < 4) ? v0[x] : v1[x - 4];
                        unsigned short ch, cl;
                        split2h((sA[d] + bv) + scb[d], ch, cl);
                        hs[x] = (short)ch;
                        ls[x] = (short)cl;
                    }
                    *(short8*)&sChi[row][cb0 + g * 8] = hs;
                    *(short8*)&sClo[row][cb0 + g * 8] = ls;
                }
            }
            __syncthreads();

            for (int i = 0; i < NB_; ++i) {
                const int bi = m * NB_ + i;
                f32x16 accC0 = zero16();   // GEMM2 acc, rows 0..31
                f32x16 accC1 = zero16();   // rows 32..63

                #pragma unroll
                for (int hf = 0; hf < 2; ++hf) {
                    // ---- GEMM1 half: h[0:64][hf*128 + jc] ----
                    {
                        const int jc = wid * 32 + l31;
                        const unsigned short* pAh =
                            w1hpk + ((size_t)((bi * 8 + hf * 4 + wid) * 8)) * 512 + loff;
                        const unsigned short* pAl =
                            w1lpk + ((size_t)((bi * 8 + hf * 4 + wid) * 8)) * 512 + loff;
                        half8 wv[16];
                        #pragma unroll
                        for (int kt = 0; kt < 8; ++kt) {
                            wv[2 * kt]     = *(const half8*)(pAh + kt * 512);
                            wv[2 * kt + 1] = *(const half8*)(pAl + kt * 512);
                        }
                        f32x16 a0 = zero16(), a1 = zero16();
                        #pragma unroll
                        for (int kt = 0; kt < 8; ++kt) {
                            half8 ah0 = *(const half8*)&sChi[l31][kt * 16 + koff];
                            half8 al0 = *(const half8*)&sClo[l31][kt * 16 + koff];
                            half8 ah1 = *(const half8*)&sChi[32 + l31][kt * 16 + koff];
                            half8 al1 = *(const half8*)&sClo[32 + l31][kt * 16 + koff];
                            a0 = __builtin_amdgcn_mfma_f32_32x32x16_f16(ah0, wv[2 * kt], a0, 0, 0, 0);
                            a1 = __builtin_amdgcn_mfma_f32_32x32x16_f16(ah1, wv[2 * kt], a1, 0, 0, 0);
                            a0 = __builtin_amdgcn_mfma_f32_32x32x16_f16(ah0, wv[2 * kt + 1], a0, 0, 0, 0);
                            a1 = __builtin_amdgcn_mfma_f32_32x32x16_f16(ah1, wv[2 * kt + 1], a1, 0, 0, 0);
                            a0 = __builtin_amdgcn_mfma_f32_32x32x16_f16(al0, wv[2 * kt], a0, 0, 0, 0);
                            a1 = __builtin_amdgcn_mfma_f32_32x32x16_f16(al1, wv[2 * kt], a1, 0, 0, 0);
                        }
                        const float b1v = b1[(size_t)bi * H_ + hf * 128 + jc];
                        #pragma unroll
                        for (int reg = 0; reg < 16; ++reg) {
                            const int krow = (reg & 3) + 8 * (reg >> 2) + 4 * (lane >> 5);
                            sHh[krow][jc]      = f2h(fmaxf(a0[reg] + b1v, 0.0f));
                            sHh[32 + krow][jc] = f2h(fmaxf(a1[reg] + b1v, 0.0f));
                        }
                    }
                    __syncthreads();

                    // ---- GEMM2 partial: accC += h_half @ W2_half^T ----
                    {
                        const unsigned short* pdh =
                            w2hpk + ((size_t)((bi * 4 + wid) * 16 + hf * 8)) * 512 + loff;
                        const unsigned short* pdl =
                            w2lpk + ((size_t)((bi * 4 + wid) * 16 + hf * 8)) * 512 + loff;
                        half8 wh[8], wl[8];
                        #pragma unroll
                        for (int s = 0; s < 8; ++s) {
                            wh[s] = *(const half8*)(pdh + s * 512);
                            wl[s] = *(const half8*)(pdl + s * 512);
                        }
                        #pragma unroll
                        for (int s = 0; s < 8; ++s) {
                            half8 h0 = *(const half8*)&sHh[l31][s * 16 + koff];
                            half8 h1 = *(const half8*)&sHh[32 + l31][s * 16 + koff];
                            accC0 = __builtin_amdgcn_mfma_f32_32x32x16_f16(h0, wh[s], accC0, 0, 0, 0);
                            accC1 = __builtin_amdgcn_mfma_f32_32x32x16_f16(h1, wh[s], accC1, 0, 0, 0);
                            accC0 = __builtin_amdgcn_mfma_f32_32x32x16_f16(h0, wl[s], accC0, 0, 0, 0);
                            accC1 = __builtin_amdgcn_mfma_f32_32x32x16_f16(h1, wl[s], accC1, 0, 0, 0);
                        }
                    }
                    __syncthreads();   // hf=0: sHh reused by next half's GEMM1
                }

                // ---- C update (per-wave disjoint columns; no extra barrier) ----
                {
                    const int d = wid * 32 + l31;
                    const float b2v = b2[(size_t)bi * D_ + d];
                    #pragma unroll
                    for (int reg = 0; reg < 16; ++reg) {
                        const int krow = (reg & 3) + 8 * (reg >> 2) + 4 * (lane >> 5);
                        {
                            const float cvo = s2f(sChi[krow][d]) + s2f(sClo[krow][d]);
                            const float cv  = (cvo + accC0[reg]) + b2v;
                            unsigned short ch, cl;
                            split2h(cv, ch, cl);
                            sChi[krow][d] = ch;
                            sClo[krow][d] = cl;
                        }
                        {
                            const int r2 = 32 + krow;
                            const float cvo = s2f(sChi[r2][d]) + s2f(sClo[r2][d]);
                            const float cv  = (cvo + accC1[reg]) + b2v;
                            unsigned short ch, cl;
                            split2h(cv, ch, cl);
                            sChi[r2][d] = ch;
                            sClo[r2][d] = cl;
                        }
                    }
                }
                __syncthreads();
            }

            // ---- fast dists for this tile ----
            {
                const int row = t >> 2, seg = t & 3;
                float qa = 0.f;
                #pragma unroll
                for (int dd = 0; dd < 32; ++dd) {
                    const int d = seg * 32 + dd;
                    const float cv = s2f(sChi[row][d]) + s2f(sClo[row][d]);
                    const float e = sr[d] - cv;
                    qa = fmaf(e, e, qa);
                }
                qa += __shfl_xor(qa, 1);
                qa += __shfl_xor(qa, 2);
                if (seg == 0) sdist[k0 + row] = qa;
            }
            __syncthreads();
        }

        // ================= refine: serial exact f64 candidates =============
        if (t < 64) {
            float bv = fminf(fminf(sdist[t], sdist[t + 64]),
                             fminf(sdist[t + 128], sdist[t + 192]));
            #pragma unroll
            for (int s = 1; s < 64; s <<= 1) bv = fminf(bv, __shfl_xor(bv, s));
            if (t == 0) { smin = bv; sbest = 1e30f; sbidx = 0; }
        }
        __syncthreads();
        const float thr = smin + EPS_;

        for (int k = 0; k < K_; ++k) {
            if (sdist[k] > thr) continue;   // uniform branch
            if (t < D_)
                sE[t] = (sA[t] + Bb[((size_t)(m * K_ + k)) * D_ + t]) + scb[t];
            __syncthreads();
            for (int i = 0; i < NB_; ++i) {
                const int bi = m * NB_ + i;
                {
                    const f32x4* wp = (const f32x4*)(w1 + ((size_t)bi * H_ + t) * D_);
                    double h0 = 0, h1 = 0, h2 = 0, h3 = 0;
                    #pragma unroll 8
                    for (int u = 0; u < 32; ++u) {
                        f32x4 wv = wp[u];
                        h0 += (double)(sE[u * 4 + 0] * wv[0]);
                        h1 += (double)(sE[u * 4 + 1] * wv[1]);
                        h2 += (double)(sE[u * 4 + 2] * wv[2]);
                        h3 += (double)(sE[u * 4 + 3] * wv[3]);
                    }
                    const float hv = (float)((h0 + h1) + (h2 + h3)) + b1[(size_t)bi * H_ + t];
                    shrow[t] = fmaxf(hv, 0.0f);
                }
                __syncthreads();
                if (t < D_) {
                    const f32x4* wp = (const f32x4*)(w2 + ((size_t)bi * D_ + t) * H_);
                    double s0 = 0, s1 = 0, s2 = 0, s3 = 0;
                    #pragma unroll 8
                    for (int u = 0; u < 64; ++u) {
                        f32x4 wv = wp[u];
                        s0 += (double)(shrow[u * 4 + 0] * wv[0]);
                        s1 += (double)(shrow[u * 4 + 1] * wv[1]);
                        s2 += (double)(shrow[u * 4 + 2] * wv[2]);
                        s3 += (double)(shrow[u * 4 + 3] * wv[3]);
                    }
                    sE[t] = (sE[t] + (float)((s0 + s1) + (s2 + s3))) + b2[(size_t)bi * D_ + t];
                }
                __syncthreads();
            }
            {
                double dp = 0.0;
                if (t < D_) {
                    const float e = sr[t] - sE[t];
                    const float e2 = e * e;
                    dp = (double)e2;
                    #pragma unroll
                    for (int s = 1; s < 64; s <<= 1) dp += __shfl_xor(dp, s);
                    if ((t & 63) == 0) sdd[t >> 6] = dp;
                }
            }
            __syncthreads();
            if (t == 0) {
                const float df = (float)(sdd[0] + sdd[1]);
                if (df < sbest) { sbest = df; sbidx = k; supd = 1; }
                else supd = 0;
            }
            __syncthreads();
            if (supd && t < D_) scsel[t] = sE[t];
            __syncthreads();
        }

        if (t == 0) out1[(size_t)n * M_ + m] = (float)sbidx;

        // ---- outputs + x_hat update ----
        if (t < D_) {
            const float cs = scsel[t];
            out3[((size_t)m * N_ + n) * D_ + t] = cs;
            const float xnew = sxhat[t] + cs;
            sxhat[t] = xnew;
            if (m == M_ - 1) {
                const float zv = z[(size_t)n * D_ + t];
                out0[(size_t)n * D_ + t] = zv + (xnew - zv);
            }
        }
        __syncthreads();

        // ---- A update for next m (exact f64) ----
        if (m < M_ - 1 && t < D_) {
            const f32x4* wp = (const f32x4*)(cp_w + ((size_t)((m + 1) * D_ + t)) * (2 * D_));
            double a0 = 0, a1 = 0, a2 = 0, a3 = 0;
            #pragma unroll 8
            for (int u = 0; u < 32; ++u) {
                f32x4 wv = wp[u];
                a0 += (double)(sxhat[u * 4 + 0] * wv[0]);
                a1 += (double)(sxhat[u * 4 + 1] * wv[1]);
                a2 += (double)(sxhat[u * 4 + 2] * wv[2]);
                a3 += (double)(sxhat[u * 4 + 3] * wv[3]);
            }
            sA[t] = (float)((a0 + a1) + (a2 + a3));
        }
        __syncthreads();
    }
}

extern "C" void kernel_launch(void* const* d_in, const int* in_sizes, int n_in,
                              void* d_out, int out_size, void* d_ws, size_t ws_size,
                              hipStream_t stream) {
    const float* z       = (const float*)d_in[0];
    const float* base_cb = (const float*)d_in[1];
    const float* cp_w    = (const float*)d_in[2];
    const float* cp_b    = (const float*)d_in[3];
    const float* w1      = (const float*)d_in[4];
    const float* b1      = (const float*)d_in[5];
    const float* w2      = (const float*)d_in[6];
    const float* b2      = (const float*)d_in[7];

    float* out  = (float*)d_out;
    float* out0 = out;
    float* out1 = out0 + (size_t)N_ * D_;
    float* out2 = out1 + (size_t)N_ * M_;
    float* out3 = out2 + (size_t)M_ * N_ * D_;

    char* ws = (char*)d_ws;
    float*          Bb    = (float*)(ws + 0);
    unsigned short* w1hpk = (unsigned short*)(ws + 524288);
    unsigned short* w1lpk = (unsigned short*)(ws + 1048576);
    unsigned short* w2hpk = (unsigned short*)(ws + 1572864);
    unsigned short* w2lpk = (unsigned short*)(ws + 2097152);

    hipLaunchKernelGGL(precompute_Bb, dim3(M_ * K_), dim3(D_), 0, stream,
                       base_cb, cp_w, Bb);
    hipLaunchKernelGGL(convert_w, dim3(1024), dim3(256), 0, stream,
                       w1, w2, w1hpk, w1lpk, w2hpk, w2lpk);
    hipLaunchKernelGGL(mega_kernel, dim3(N_), dim3(256), 0, stream,
                       z, cp_w, cp_b, w1, b1, w2, b2, Bb,
                       w1hpk, w1lpk, w2hpk, w2lpk,
                       out0, out1, out2, out3);
}